// Round 2
// baseline (166.215 us; speedup 1.0000x reference)
//
#include <hip/hip_runtime.h>
#include <hip/hip_bf16.h>

// ClusterLoss fused kernel for MI355X (gfx950).  R9.
// Lesson R8: 1024-thread blocks pin the allocator at 64 VGPR (confirmed twice)
// -> 61 MB scratch spill. Occupancy must come from MORE BLOCKS, not bigger ones.
// R9 = R7 algorithm but B split into two 512-center halves (64 KB each) and
// 64-row A tiles (8 KB): 77.8 KB LDS/block -> 2 blocks/CU -> 4 waves/SIMD at
// the proven spill-free 512-thread shape. Each block passes twice over its
// 256 rows (once per B-half), keeping per-row running keyed-max in LDS.
// Features re-read on pass 2 is L3-resident (64 MB < 256 MB Infinity Cache).
// loss_n = 1 - 2 d na/nf + na^2 (fp32 scalars).

#define D 128
#define NK 1024
#define HALFK 512
#define ROWT 64

typedef __attribute__((ext_vector_type(4))) float floatx4;

template <bool HI>
__device__ __forceinline__ unsigned int pk_fp8(float a, float b, unsigned int old) {
    return (unsigned int)__builtin_amdgcn_cvt_pk_fp8_f32(a, b, (int)old, HI);
}

__device__ __forceinline__ float key_pack(float v, unsigned int inv_k) {
    unsigned int u = __builtin_bit_cast(unsigned int, v);
    unsigned int r = (0x3FFu & inv_k) | (~0x3FFu & u);   // v_bfi_b32
    return __builtin_bit_cast(float, r);
}

// ---- Prep: normalize centers -> fp8 chat, store fp32 norms; zero d_out ----
__global__ void prep_centers(const float* __restrict__ centers,
                             unsigned char* __restrict__ chat,
                             float* __restrict__ cnorm,
                             float* __restrict__ out) {
    const int k = blockIdx.x;
    const int t = threadIdx.x;            // 128 threads, one per dim
    float v = centers[(size_t)k * D + t];
    float s = v * v;
    #pragma unroll
    for (int m = 1; m <= 32; m <<= 1) s += __shfl_xor(s, m);
    __shared__ float ws2[2];
    if ((t & 63) == 0) ws2[t >> 6] = s;
    __syncthreads();
    float total = ws2[0] + ws2[1];
    float n = sqrtf(total);
    float neff = fmaxf(n, 1e-12f);
    float q = v / neff;
    chat[(size_t)k * D + t] = (unsigned char)(pk_fp8<false>(q, q, 0u) & 0xFFu);
    if (t == 0) cnorm[k] = n;
    if (k == 0 && t == 0) out[0] = 0.0f;
}

// ---- Main ----
__global__ __launch_bounds__(512, 4) void cluster_main(
    const float* __restrict__ feats,        // [N][128] fp32
    const unsigned char* __restrict__ chat, // [1024][128] fp8 e4m3
    const float* __restrict__ cnorm,        // [1024] fp32
    float* __restrict__ out, int N, int rtPer) {

    extern __shared__ unsigned char lds[];
    unsigned char* Bs = lds;                 // 65536 B, swizzled (512 centers)
    unsigned char* As = lds + HALFK * D;     // 8192 B, swizzled (64 rows)
    __shared__ float nf_s[256];              // per-row sumsq (block's 256 rows)
    __shared__ float best_s[256];            // running keyed max across halves
    __shared__ float bv[8][64];              // per-wave keyed max per row

    const int tid  = threadIdx.x;            // 0..511, 8 waves
    const int lane = tid & 63;
    const int wn   = tid >> 6;               // wave = col slice (64 centers)
    const int m16  = lane & 15;
    const int quad = lane >> 4;              // 0..3
    const int q1   = quad >> 1, q0 = quad & 1;
    const int m8   = m16 & 7;
    const int rowBase = blockIdx.x * (rtPer * ROWT);

    for (int half = 0; half < 2; ++half) {
        // ---- Stage B half: 4096 16B chunks, 8/thread, swizzled ----
        #pragma unroll
        for (int s = 0; s < 8; ++s) {
            int id = s * 512 + tid;
            int r  = id >> 3;                // local center row 0..511
            int c  = id & 7;                 // logical 16B chunk
            uint4 v = *(const uint4*)(chat + (size_t)(half * HALFK + r) * D + c * 16);
            *(uint4*)&Bs[r * D + ((c ^ (r & 7)) << 4)] = v;
        }

        for (int rt = 0; rt < rtPer; ++rt) {
            const int row0 = rowBase + rt * ROWT;

            // ---- Stage A (coalesced float4 -> fp8, swizzled) + row sumsq ----
            #pragma unroll
            for (int s = 0; s < 4; ++s) {
                int id = s * 512 + tid;      // float4 chunk, 0..2047
                int r  = id >> 5;            // local row 0..63
                int c4 = id & 31;
                float4 v = *(const float4*)(feats + (size_t)(row0 + r) * D + c4 * 4);
                unsigned int w = pk_fp8<false>(v.x, v.y, 0u);
                w = pk_fp8<true>(v.z, v.w, w);
                int pc = (c4 >> 2) ^ (r & 7);
                *(unsigned int*)&As[r * D + pc * 16 + (c4 & 3) * 4] = w;
                float sq = v.x*v.x + v.y*v.y + v.z*v.z + v.w*v.w;
                #pragma unroll
                for (int m = 1; m <= 16; m <<= 1) sq += __shfl_xor(sq, m);
                if ((tid & 31) == 0) nf_s[rt * ROWT + r] = sq;
            }
            __syncthreads();                 // Bs + As + nf_s visible

            // ---- A fragments from LDS ----
            long long afr[4][4];             // [i][kk], i covers 64 rows
            #pragma unroll
            for (int i = 0; i < 4; ++i) {
                const int r = i * 16 + m16;
                #pragma unroll
                for (int kk = 0; kk < 4; ++kk) {
                    int pc = (2 * kk + q1) ^ m8;
                    afr[i][kk] = *(const long long*)&As[r * D + pc * 16 + q0 * 8];
                }
            }

            float best[16];                  // keyed floats, per (i,r) slot
            #pragma unroll
            for (int s = 0; s < 16; ++s) best[s] = -3.0e38f;

            // ---- barrier-free MFMA over this wave's 64-center slice ----
            #pragma unroll
            for (int ch = 0; ch < 2; ++ch) { // 2 chunks of 32 centers
                const int cl = wn * 64 + ch * 32;    // local center base
                const unsigned int inv0 =
                    1023u - (unsigned)(half * HALFK + cl + m16);     // j=0
                const unsigned int inv1 = inv0 - 16u;                // j=1
                floatx4 acc[4][2];
                #pragma unroll
                for (int i = 0; i < 4; ++i)
                    #pragma unroll
                    for (int j = 0; j < 2; ++j)
                        acc[i][j] = (floatx4){0.f, 0.f, 0.f, 0.f};

                #pragma unroll
                for (int kk = 0; kk < 4; ++kk) {
                    long long bfr[2];
                    #pragma unroll
                    for (int j = 0; j < 2; ++j) {
                        int k  = cl + j * 16 + m16;
                        int pc = (2 * kk + q1) ^ m8;
                        bfr[j] = *(const long long*)&Bs[k * D + pc * 16 + q0 * 8];
                    }
                    #pragma unroll
                    for (int i = 0; i < 4; ++i)
                        #pragma unroll
                        for (int j = 0; j < 2; ++j)
                            acc[i][j] = __builtin_amdgcn_mfma_f32_16x16x32_fp8_fp8(
                                afr[i][kk], bfr[j], acc[i][j], 0, 0, 0);
                }

                // keyed argmax: bfi + max per candidate pair
                #pragma unroll
                for (int i = 0; i < 4; ++i)
                    #pragma unroll
                    for (int r = 0; r < 4; ++r) {
                        const int slot = i * 4 + r;
                        float c0 = key_pack(acc[i][0][r], inv0);
                        float c1 = key_pack(acc[i][1][r], inv1);
                        best[slot] = fmaxf(best[slot], fmaxf(c0, c1));
                    }
            }

            // cross-m16 butterfly (same rows, different cols)
            #pragma unroll
            for (int mask = 1; mask <= 8; mask <<= 1)
                #pragma unroll
                for (int s = 0; s < 16; ++s)
                    best[s] = fmaxf(best[s], __shfl_xor(best[s], mask));

            if (m16 == 0) {
                #pragma unroll
                for (int s = 0; s < 16; ++s) {
                    int i = s >> 2, rr = s & 3;
                    int row = 16 * i + quad * 4 + rr;   // local row 0..63
                    bv[wn][row] = best[s];
                }
            }
            __syncthreads();                 // bv visible; all As/Bs reads done

            // ---- combine 8 col-slices into running per-row best ----
            if (tid < 64) {
                float k01 = fmaxf(bv[0][tid], bv[1][tid]);
                float k23 = fmaxf(bv[2][tid], bv[3][tid]);
                float k45 = fmaxf(bv[4][tid], bv[5][tid]);
                float k67 = fmaxf(bv[6][tid], bv[7][tid]);
                float kmax = fmaxf(fmaxf(k01, k23), fmaxf(k45, k67));
                int idx = rt * ROWT + tid;
                best_s[idx] = (half == 0) ? kmax : fmaxf(best_s[idx], kmax);
            }
            // no trailing barrier needed: next phase writes As/nf_s/Bs only,
            // disjoint from bv/best_s read here; bv rewritten only after the
            // next __syncthreads().
        }
    }

    __syncthreads();                         // best_s final + visible

    // ---- decode; loss; reduce (256 rows, 4 waves) ----
    if (tid < 256) {
        const int row = tid;
        unsigned int ub = __builtin_bit_cast(unsigned int, best_s[row]);
        int   ka = 1023 - (int)(ub & 1023u);
        float d  = __builtin_bit_cast(float, (ub & 0xFFFFFC00u) | 0x200u);
        float nf = fmaxf(sqrtf(nf_s[row]), 1e-12f);
        float na = cnorm[ka];
        float lsum = 1.0f - 2.0f * d * na / nf + na * na;
        #pragma unroll
        for (int m = 1; m <= 32; m <<= 1) lsum += __shfl_xor(lsum, m);
        if (lane == 0) atomicAdd(out, lsum / (float)N);
    }
}

extern "C" void kernel_launch(void* const* d_in, const int* in_sizes, int n_in,
                              void* d_out, int out_size, void* d_ws, size_t ws_size,
                              hipStream_t stream) {
    const float* feats   = (const float*)d_in[0];
    const float* centers = (const float*)d_in[1];
    const int N = in_sizes[0] / D;   // 131072
    const int K = in_sizes[1] / D;   // 1024

    unsigned char* chat = (unsigned char*)d_ws;                    // 1024*128 fp8 = 128 KB
    float* cnorm = (float*)((char*)d_ws + (size_t)K * D);          // K fp32
    float* out = (float*)d_out;

    const int smem = HALFK * D + ROWT * D;   // 73728 B dynamic (77.8 KB w/ static)
    (void)hipFuncSetAttribute((const void*)cluster_main,
                              hipFuncAttributeMaxDynamicSharedMemorySize, smem);

    prep_centers<<<K, D, 0, stream>>>(centers, chat, cnorm, out);

    const int grid = 512;                    // 2 blocks/CU x 256 CU
    const int rtPer = (N / ROWT) / grid;     // 4 row tiles of 64
    cluster_main<<<grid, 512, smem, stream>>>(feats, chat, cnorm, out, N, rtPer);
}